// Round 2
// baseline (35932.526 us; speedup 1.0000x reference)
//
#include <hip/hip_runtime.h>
#include <cstddef>
#include <cstdint>

namespace {

constexpr int B = 256, S = 128, H = 512;
constexpr int NBLK = 256;   // persistent grid size (1 block per CU)
constexpr int NTHR = 512;   // 8 waves per CU

__device__ __forceinline__ float sigmf(float x) { return 1.f / (1.f + expf(-x)); }

// ---------------------------------------------------------------------------
// init: h <- h0, c <- c0, mask <- 1, barrier counters <- 0
// ---------------------------------------------------------------------------
__global__ __launch_bounds__(512) void init_kernel(float* __restrict__ h,
                                                   float* __restrict__ c,
                                                   float* __restrict__ mask,
                                                   int* __restrict__ bar,
                                                   const float* __restrict__ h0,
                                                   const float* __restrict__ c0) {
  int tid = blockIdx.x * 512 + threadIdx.x;
  if (tid < B * H) {
    h[tid] = h0[tid];
    c[tid] = c0[tid];
  }
  if (tid < B * S) mask[tid] = 1.0f;
  if (tid < 2) bar[tid] = 0;
}

// ---------------------------------------------------------------------------
// Precompute GEMM: C = A @ Bw   (ctx_proj), fp32, row-major.
// ---------------------------------------------------------------------------
template <int BM, int BN, int TM, int TN, int KT>
__global__ __launch_bounds__((BM / TM) * (BN / TN)) void gemm_pre(
    const float* __restrict__ A, const float* __restrict__ Bw,
    float* __restrict__ C, int M, int N, int K) {
  constexpr int THREADS = (BM / TM) * (BN / TN);
  const int tid = threadIdx.x;
  const int n0 = blockIdx.x * BN;
  const int m0 = blockIdx.y * BM;

  __shared__ float As[KT][BM + 4];
  __shared__ float Bs[KT][BN];

  float acc[TM][TN];
#pragma unroll
  for (int i = 0; i < TM; ++i)
#pragma unroll
    for (int j = 0; j < TN; ++j) acc[i][j] = 0.f;

  const int tn = tid % (BN / TN);
  const int tm = tid / (BN / TN);

  for (int kk = 0; kk < K; kk += KT) {
    for (int idx = tid; idx < BM * (KT / 4); idx += THREADS) {
      int row = idx / (KT / 4), kq = idx % (KT / 4);
      float4 a4 = *reinterpret_cast<const float4*>(A + (size_t)(m0 + row) * K + kk + kq * 4);
      As[kq * 4 + 0][row] = a4.x;
      As[kq * 4 + 1][row] = a4.y;
      As[kq * 4 + 2][row] = a4.z;
      As[kq * 4 + 3][row] = a4.w;
    }
    for (int idx = tid; idx < KT * (BN / 4); idx += THREADS) {
      int k = idx / (BN / 4), n4 = idx % (BN / 4);
      *reinterpret_cast<float4*>(&Bs[k][n4 * 4]) =
          *reinterpret_cast<const float4*>(Bw + (size_t)(kk + k) * N + n0 + n4 * 4);
    }
    __syncthreads();
#pragma unroll
    for (int k = 0; k < KT; ++k) {
      float a[TM], bb[TN];
#pragma unroll
      for (int i = 0; i < TM; ++i) a[i] = As[k][tm * TM + i];
#pragma unroll
      for (int j = 0; j < TN; ++j) bb[j] = Bs[k][tn * TN + j];
#pragma unroll
      for (int i = 0; i < TM; ++i)
#pragma unroll
        for (int j = 0; j < TN; ++j) acc[i][j] = fmaf(a[i], bb[j], acc[i][j]);
    }
    __syncthreads();
  }
#pragma unroll
  for (int i = 0; i < TM; ++i)
#pragma unroll
    for (int j = 0; j < TN; ++j)
      C[(size_t)(m0 + tm * TM + i) * N + n0 + tn * TN + j] = acc[i][j];
}

// ---------------------------------------------------------------------------
// Device-scope grid barrier (generation counter). All NBLK blocks, all
// threads call it. bar[0] = arrive count, bar[1] = generation.
// ---------------------------------------------------------------------------
__device__ __forceinline__ void grid_barrier(int* __restrict__ bar) {
  __syncthreads();
  if (threadIdx.x == 0) {
    __threadfence();  // release: publish this block's writes device-wide
    int g0 = __hip_atomic_load(&bar[1], __ATOMIC_RELAXED, __HIP_MEMORY_SCOPE_AGENT);
    int prev = __hip_atomic_fetch_add(&bar[0], 1, __ATOMIC_ACQ_REL, __HIP_MEMORY_SCOPE_AGENT);
    if (prev == NBLK - 1) {
      __hip_atomic_store(&bar[0], 0, __ATOMIC_RELAXED, __HIP_MEMORY_SCOPE_AGENT);
      __hip_atomic_fetch_add(&bar[1], 1, __ATOMIC_RELEASE, __HIP_MEMORY_SCOPE_AGENT);
    } else {
      while (__hip_atomic_load(&bar[1], __ATOMIC_ACQUIRE, __HIP_MEMORY_SCOPE_AGENT) == g0) {
        __builtin_amdgcn_s_sleep(2);
      }
    }
    __threadfence();  // acquire: invalidate stale cached lines
  }
  __syncthreads();
}

// ---------------------------------------------------------------------------
// Persistent decoder: all 128 steps, 4 phases per step, grid barriers between.
// Grid: 256 blocks x 512 threads (1 block/CU, co-resident by construction).
// ---------------------------------------------------------------------------
__global__ __launch_bounds__(NTHR) void decoder_fused(
    const float* __restrict__ emb, const float* __restrict__ dec,
    const float* __restrict__ ctx, const float* __restrict__ Wi,
    const float* __restrict__ bi, const float* __restrict__ Wh,
    const float* __restrict__ bh, const float* __restrict__ Wha,
    const float* __restrict__ v, const float* __restrict__ Wout,
    const float* __restrict__ bout, const float* __restrict__ ctxp,
    float* __restrict__ gates, float* __restrict__ g_h,
    float* __restrict__ c0buf, float* __restrict__ c1buf,
    float* __restrict__ g_q, float* __restrict__ g_hp,
    float* __restrict__ g_att, float* __restrict__ g_msk,
    int* __restrict__ g_sel, int* __restrict__ bar,
    float* __restrict__ out) {
  const int bid = blockIdx.x;
  const int tid = threadIdx.x;

  __shared__ union {
    struct { float As[64][36]; float Bs[64][64]; } p1;                 // 25.6 KB
    struct { float hi[16][512]; float Bs[64][68]; } p2;                // 50.2 KB
    struct { float qs[512]; float vs[512]; float sc[128]; float al[128];
             float red[4]; int redi[4]; } p3;                          // ~5.2 KB
    struct { float As[64][36]; float Bs[64][20]; } p4;                 // 14.3 KB
  } sh;

  for (int t = 0; t < S; ++t) {
    const float* cr = (t & 1) ? c1buf : c0buf;
    float* cw = (t & 1) ? c0buf : c1buf;

    // ============ P1: gates = h@Wh + gather(x)@Wi + bi + bh ============
    {
      const int m0 = (bid >> 5) * 32;   // 8 m-tiles of 32 rows
      const int n0 = (bid & 31) * 64;   // 32 n-tiles of 64 cols (N=2048)
      const int tm = tid >> 5;          // 0..15
      const int tn = tid & 31;          // 0..31
      float acc00 = 0.f, acc01 = 0.f, acc10 = 0.f, acc11 = 0.f;

      const int srow = tid >> 4;          // 0..31 (staging row)
      const int skq = (tid & 15) * 4;     // 0..60 (staging k quad)

      for (int part = 0; part < 2; ++part) {
        const float* Wp = part ? Wi : Wh;
        // A row pointer for staging
        const float* ar;
        if (part == 0) {
          ar = g_h + (size_t)(m0 + srow) * H;
        } else if (t == 0) {
          ar = dec + (size_t)(m0 + srow) * H;
        } else {
          ar = emb + ((size_t)(m0 + srow) * S + g_sel[m0 + srow]) * H;
        }
        for (int kk = 0; kk < H; kk += 64) {
          float4 a4 = *reinterpret_cast<const float4*>(ar + kk + skq);
          sh.p1.As[skq + 0][srow] = a4.x;
          sh.p1.As[skq + 1][srow] = a4.y;
          sh.p1.As[skq + 2][srow] = a4.z;
          sh.p1.As[skq + 3][srow] = a4.w;
#pragma unroll
          for (int i = 0; i < 2; ++i) {
            int lin = tid + i * 512;
            int k = lin >> 4, c4 = (lin & 15) * 4;
            *reinterpret_cast<float4*>(&sh.p1.Bs[k][c4]) =
                *reinterpret_cast<const float4*>(Wp + (size_t)(kk + k) * 2048 + n0 + c4);
          }
          __syncthreads();
#pragma unroll 8
          for (int k = 0; k < 64; ++k) {
            float2 a = *reinterpret_cast<const float2*>(&sh.p1.As[k][tm * 2]);
            float2 b = *reinterpret_cast<const float2*>(&sh.p1.Bs[k][tn * 2]);
            acc00 = fmaf(a.x, b.x, acc00);
            acc01 = fmaf(a.x, b.y, acc01);
            acc10 = fmaf(a.y, b.x, acc10);
            acc11 = fmaf(a.y, b.y, acc11);
          }
          __syncthreads();
        }
      }
      const int r0 = m0 + tm * 2, cA = n0 + tn * 2;
      float bb0 = bi[cA] + bh[cA], bb1 = bi[cA + 1] + bh[cA + 1];
      *reinterpret_cast<float2*>(&gates[(size_t)r0 * 2048 + cA]) =
          make_float2(acc00 + bb0, acc01 + bb1);
      *reinterpret_cast<float2*>(&gates[(size_t)(r0 + 1) * 2048 + cA]) =
          make_float2(acc10 + bb0, acc11 + bb1);
    }
    grid_barrier(bar);

    // ============ P2: cell (into LDS) + [q | hpart] = h_i @ [Wha | Wout2] ====
    {
      const int mt = bid >> 4, nt = bid & 15;
      const int m0 = mt * 16;
      const bool isq = nt < 8;
      const float* Wp = isq ? Wha : (Wout + (size_t)H * H);
      const int n0 = (isq ? nt : nt - 8) * 64;
      float* Co = isq ? g_q : g_hp;

      // LSTM cell for this block's 16 rows -> h_i tile in LDS
      for (int r = 0; r < 16; ++r) {
        size_t gb = (size_t)(m0 + r) * 2048 + tid;
        float gi = sigmf(gates[gb]);
        float gf = sigmf(gates[gb + 512]);
        float gg = sigmf(gates[gb + 1024]);
        float go = sigmf(gates[gb + 1536]);
        float cn = gf * cr[(size_t)(m0 + r) * H + tid] + gi * gg;
        if (nt == 0) cw[(size_t)(m0 + r) * H + tid] = cn;
        sh.p2.hi[r][tid] = go * tanhf(cn);
      }
      __syncthreads();

      const int tm = tid >> 5;   // 0..15
      const int tn = tid & 31;   // 0..31
      float a0 = 0.f, a1 = 0.f;
      for (int kk = 0; kk < H; kk += 64) {
#pragma unroll
        for (int i = 0; i < 2; ++i) {
          int lin = tid + i * 512;
          int k = lin >> 4, c4 = (lin & 15) * 4;
          *reinterpret_cast<float4*>(&sh.p2.Bs[k][c4]) =
              *reinterpret_cast<const float4*>(Wp + (size_t)(kk + k) * H + n0 + c4);
        }
        __syncthreads();
#pragma unroll 8
        for (int k = 0; k < 64; ++k) {
          float av = sh.p2.hi[tm][kk + k];
          float2 b = *reinterpret_cast<const float2*>(&sh.p2.Bs[k][tn * 2]);
          a0 = fmaf(av, b.x, a0);
          a1 = fmaf(av, b.y, a1);
        }
        __syncthreads();
      }
      *reinterpret_cast<float2*>(&Co[(size_t)(m0 + tm) * H + n0 + tn * 2]) =
          make_float2(a0, a1);
    }
    grid_barrier(bar);

    // ============ P3: attention (one block per batch row) ============
    {
      const int b = bid;
      sh.p3.qs[tid] = g_q[(size_t)b * H + tid];
      sh.p3.vs[tid] = v[tid];
      __syncthreads();

      // scores: 4 threads per s, 128 h each
      const int s = tid >> 2, qtr = tid & 3, hb = qtr * 128;
      const float* cp = ctxp + ((size_t)b * S + s) * H + hb;
      float p = 0.f;
#pragma unroll 8
      for (int i = 0; i < 128; i += 4) {
        float4 c4 = *reinterpret_cast<const float4*>(cp + i);
        p += sh.p3.vs[hb + i + 0] * tanhf(c4.x + sh.p3.qs[hb + i + 0]);
        p += sh.p3.vs[hb + i + 1] * tanhf(c4.y + sh.p3.qs[hb + i + 1]);
        p += sh.p3.vs[hb + i + 2] * tanhf(c4.z + sh.p3.qs[hb + i + 2]);
        p += sh.p3.vs[hb + i + 3] * tanhf(c4.w + sh.p3.qs[hb + i + 3]);
      }
      p += __shfl_xor(p, 1);
      p += __shfl_xor(p, 2);
      if (qtr == 0) {
        float mk = g_msk[(size_t)b * S + s];
        sh.p3.sc[s] = (mk == 0.f) ? -1e9f : p;
      }
      __syncthreads();

      // softmax over 128 (threads 0..127 = 2 waves)
      float sval = 0.f, maskv = 0.f, e = 0.f, a = 0.f;
      if (tid < 128) {
        sval = sh.p3.sc[tid];
        maskv = g_msk[(size_t)b * S + tid];
      }
      float wm = (tid < 128) ? sval : -3.0e38f;
      for (int o = 1; o < 64; o <<= 1) wm = fmaxf(wm, __shfl_xor(wm, o));
      if (tid < 128 && (tid & 63) == 0) sh.p3.red[tid >> 6] = wm;
      __syncthreads();
      float m = fmaxf(sh.p3.red[0], sh.p3.red[1]);
      if (tid < 128) e = expf(sval - m);
      float wsum = (tid < 128) ? e : 0.f;
      for (int o = 1; o < 64; o <<= 1) wsum += __shfl_xor(wsum, o);
      if (tid < 128 && (tid & 63) == 0) sh.p3.red[tid >> 6] = wsum;
      __syncthreads();
      float sum = sh.p3.red[0] + sh.p3.red[1];
      if (tid < 128) {
        a = e / sum;
        sh.p3.al[tid] = a;
        out[((size_t)b * S + t) * S + tid] = a;   // outputs[b, t, :]
      }

      // argmax(alpha * mask), first-index tiebreak
      float mv = (tid < 128) ? a * maskv : -1.f;
      int mi = tid & 127;
      for (int o = 1; o < 64; o <<= 1) {
        float ov = __shfl_xor(mv, o);
        int oi = __shfl_xor(mi, o);
        if (ov > mv || (ov == mv && oi < mi)) { mv = ov; mi = oi; }
      }
      if (tid < 128 && (tid & 63) == 0) {
        sh.p3.red[2 + (tid >> 6)] = mv;
        sh.p3.redi[tid >> 6] = mi;
      }
      __syncthreads();
      if (tid == 0) {
        float bv = sh.p3.red[2];
        int bI = sh.p3.redi[0];
        if (sh.p3.red[3] > bv || (sh.p3.red[3] == bv && sh.p3.redi[1] < bI)) {
          bv = sh.p3.red[3];
          bI = sh.p3.redi[1];
        }
        out[(size_t)B * S * S + (size_t)b * S + t] = (float)bI;  // pointers[b, t]
        g_msk[(size_t)b * S + bI] = 0.f;
        g_sel[b] = bI;
      }
      __syncthreads();

      // att[b, :] = sum_s alpha[s] * context[b, s, :]  (1 col/thread)
      float acc = 0.f;
      const float* cb = ctx + (size_t)b * S * H + tid;
#pragma unroll 4
      for (int s2 = 0; s2 < S; ++s2) acc = fmaf(sh.p3.al[s2], cb[(size_t)s2 * H], acc);
      g_att[(size_t)b * H + tid] = acc;
    }
    grid_barrier(bar);

    // ============ P4: h = tanh(att@Wout1 + hpart + bout) ============
    {
      const int m0 = (bid >> 5) * 32;   // 8 m-tiles of 32
      const int n0 = (bid & 31) * 16;   // 32 n-tiles of 16 (N=512)
      const int tm = tid >> 4;          // 0..31
      const int tn = tid & 15;          // 0..15
      float acc = 0.f;
      const int srow = tid >> 4, skq = (tid & 15) * 4;
      for (int kk = 0; kk < H; kk += 64) {
        float4 a4 = *reinterpret_cast<const float4*>(
            g_att + (size_t)(m0 + srow) * H + kk + skq);
        sh.p4.As[skq + 0][srow] = a4.x;
        sh.p4.As[skq + 1][srow] = a4.y;
        sh.p4.As[skq + 2][srow] = a4.z;
        sh.p4.As[skq + 3][srow] = a4.w;
        if (tid < 256) {
          int k = tid >> 2, c4 = (tid & 3) * 4;
          *reinterpret_cast<float4*>(&sh.p4.Bs[k][c4]) =
              *reinterpret_cast<const float4*>(Wout + (size_t)(kk + k) * H + n0 + c4);
        }
        __syncthreads();
#pragma unroll 8
        for (int k = 0; k < 64; ++k)
          acc = fmaf(sh.p4.As[k][tm], sh.p4.Bs[k][tn], acc);
        __syncthreads();
      }
      float x = acc + g_hp[(size_t)(m0 + tm) * H + n0 + tn] + bout[n0 + tn];
      g_h[(size_t)(m0 + tm) * H + n0 + tn] = tanhf(x);
    }
    grid_barrier(bar);
  }
}

}  // namespace

// ---------------------------------------------------------------------------
extern "C" void kernel_launch(void* const* d_in, const int* in_sizes, int n_in,
                              void* d_out, int out_size, void* d_ws, size_t ws_size,
                              hipStream_t stream) {
  const float* emb  = (const float*)d_in[0];   // (B,S,H)
  const float* dec  = (const float*)d_in[1];   // (B,H)
  const float* h0   = (const float*)d_in[2];   // (B,H)
  const float* c0   = (const float*)d_in[3];   // (B,H)
  const float* ctx  = (const float*)d_in[4];   // (B,S,H)
  const float* Wi   = (const float*)d_in[5];   // (H,4H)
  const float* bi   = (const float*)d_in[6];   // (4H)
  const float* Wh   = (const float*)d_in[7];   // (H,4H)
  const float* bh   = (const float*)d_in[8];   // (4H)
  const float* Wctx = (const float*)d_in[9];   // (H,H)
  const float* Wha  = (const float*)d_in[10];  // (H,H)
  const float* v    = (const float*)d_in[11];  // (H)
  const float* Wout = (const float*)d_in[12];  // (2H,H)
  const float* bout = (const float*)d_in[13];  // (H)
  float* out = (float*)d_out;

  // workspace layout (floats)
  float* ws = (float*)d_ws;
  float* ctxp  = ws;                            // B*S*H = 16,777,216
  float* gates = ctxp + (size_t)B * S * H;      // B*4H
  float* g_h   = gates + (size_t)B * 4 * H;     // B*H
  float* c0buf = g_h + (size_t)B * H;           // B*H
  float* c1buf = c0buf + (size_t)B * H;         // B*H
  float* g_q   = c1buf + (size_t)B * H;         // B*H
  float* g_hp  = g_q + (size_t)B * H;           // B*H
  float* g_att = g_hp + (size_t)B * H;          // B*H
  float* g_msk = g_att + (size_t)B * H;         // B*S
  int*   g_sel = (int*)(g_msk + (size_t)B * S); // B
  int*   bar   = g_sel + B;                     // 2

  init_kernel<<<(B * H + 511) / 512, 512, 0, stream>>>(g_h, c0buf, g_msk, bar, h0, c0);

  // ctx_proj = context @ Wctx   (32768 x 512, K=512)
  gemm_pre<128, 64, 8, 4, 16><<<dim3(H / 64, (B * S) / 128), 256, 0, stream>>>(
      ctx, Wctx, ctxp, B * S, H, H);

  decoder_fused<<<NBLK, NTHR, 0, stream>>>(
      emb, dec, ctx, Wi, bi, Wh, bh, Wha, v, Wout, bout, ctxp,
      gates, g_h, c0buf, c1buf, g_q, g_hp, g_att, g_msk, g_sel, bar, out);
}

// Round 3
// 30024.939 us; speedup vs baseline: 1.1968x; 1.1968x over previous
//
#include <hip/hip_runtime.h>
#include <cstddef>
#include <cstdint>

namespace {

constexpr int B = 256, S = 128, H = 512;
constexpr int NBLK = 256;   // persistent grid size (1 block per CU)
constexpr int NTHR = 512;   // 8 waves per CU

__device__ __forceinline__ float sigmf(float x) { return 1.f / (1.f + expf(-x)); }

// ---------------------------------------------------------------------------
// init: h <- h0, c <- c0, mask <- 1, barrier slots+gen <- 0
// ---------------------------------------------------------------------------
__global__ __launch_bounds__(512) void init_kernel(float* __restrict__ h,
                                                   float* __restrict__ c,
                                                   float* __restrict__ mask,
                                                   int* __restrict__ bar,
                                                   const float* __restrict__ h0,
                                                   const float* __restrict__ c0) {
  int tid = blockIdx.x * 512 + threadIdx.x;
  if (tid < B * H) {
    h[tid] = h0[tid];
    c[tid] = c0[tid];
  }
  if (tid < B * S) mask[tid] = 1.0f;
  if (tid < NBLK + 1) bar[tid] = 0;   // slots[256] + gen
}

// ---------------------------------------------------------------------------
// Precompute GEMM: C = A @ Bw   (ctx_proj), fp32, row-major.
// ---------------------------------------------------------------------------
template <int BM, int BN, int TM, int TN, int KT>
__global__ __launch_bounds__((BM / TM) * (BN / TN)) void gemm_pre(
    const float* __restrict__ A, const float* __restrict__ Bw,
    float* __restrict__ C, int M, int N, int K) {
  constexpr int THREADS = (BM / TM) * (BN / TN);
  const int tid = threadIdx.x;
  const int n0 = blockIdx.x * BN;
  const int m0 = blockIdx.y * BM;

  __shared__ float As[KT][BM + 4];
  __shared__ float Bs[KT][BN];

  float acc[TM][TN];
#pragma unroll
  for (int i = 0; i < TM; ++i)
#pragma unroll
    for (int j = 0; j < TN; ++j) acc[i][j] = 0.f;

  const int tn = tid % (BN / TN);
  const int tm = tid / (BN / TN);

  for (int kk = 0; kk < K; kk += KT) {
    for (int idx = tid; idx < BM * (KT / 4); idx += THREADS) {
      int row = idx / (KT / 4), kq = idx % (KT / 4);
      float4 a4 = *reinterpret_cast<const float4*>(A + (size_t)(m0 + row) * K + kk + kq * 4);
      As[kq * 4 + 0][row] = a4.x;
      As[kq * 4 + 1][row] = a4.y;
      As[kq * 4 + 2][row] = a4.z;
      As[kq * 4 + 3][row] = a4.w;
    }
    for (int idx = tid; idx < KT * (BN / 4); idx += THREADS) {
      int k = idx / (BN / 4), n4 = idx % (BN / 4);
      *reinterpret_cast<float4*>(&Bs[k][n4 * 4]) =
          *reinterpret_cast<const float4*>(Bw + (size_t)(kk + k) * N + n0 + n4 * 4);
    }
    __syncthreads();
#pragma unroll
    for (int k = 0; k < KT; ++k) {
      float a[TM], bb[TN];
#pragma unroll
      for (int i = 0; i < TM; ++i) a[i] = As[k][tm * TM + i];
#pragma unroll
      for (int j = 0; j < TN; ++j) bb[j] = Bs[k][tn * TN + j];
#pragma unroll
      for (int i = 0; i < TM; ++i)
#pragma unroll
        for (int j = 0; j < TN; ++j) acc[i][j] = fmaf(a[i], bb[j], acc[i][j]);
    }
    __syncthreads();
  }
#pragma unroll
  for (int i = 0; i < TM; ++i)
#pragma unroll
    for (int j = 0; j < TN; ++j)
      C[(size_t)(m0 + tm * TM + i) * N + n0 + tn * TN + j] = acc[i][j];
}

// ---------------------------------------------------------------------------
// Contention-free grid barrier:
//   - each block's leader release-stores generation g into its OWN slot
//   - wave 0 of block 0 polls all 256 slots (4 loads/lane), then
//     release-stores g into gen
//   - all leaders spin (read-only) on gen, then __threadfence + syncthreads
// No atomic RMW contention; arrivals are parallel independent-line stores.
// ---------------------------------------------------------------------------
__device__ __forceinline__ void grid_barrier(int* __restrict__ slots,
                                             int* __restrict__ genp, int g) {
  __syncthreads();
  if (threadIdx.x == 0) {
    __threadfence();  // publish this block's writes before announcing arrival
    __hip_atomic_store(&slots[blockIdx.x], g, __ATOMIC_RELEASE,
                       __HIP_MEMORY_SCOPE_AGENT);
  }
  if (blockIdx.x == 0 && threadIdx.x < 64) {
    const int base = threadIdx.x * 4;
    for (;;) {
      int s0 = __hip_atomic_load(&slots[base + 0], __ATOMIC_ACQUIRE, __HIP_MEMORY_SCOPE_AGENT);
      int s1 = __hip_atomic_load(&slots[base + 1], __ATOMIC_ACQUIRE, __HIP_MEMORY_SCOPE_AGENT);
      int s2 = __hip_atomic_load(&slots[base + 2], __ATOMIC_ACQUIRE, __HIP_MEMORY_SCOPE_AGENT);
      int s3 = __hip_atomic_load(&slots[base + 3], __ATOMIC_ACQUIRE, __HIP_MEMORY_SCOPE_AGENT);
      bool ok = (s0 >= g) && (s1 >= g) && (s2 >= g) && (s3 >= g);
      if (__all(ok)) break;
      __builtin_amdgcn_s_sleep(1);
    }
    if (threadIdx.x == 0)
      __hip_atomic_store(genp, g, __ATOMIC_RELEASE, __HIP_MEMORY_SCOPE_AGENT);
  }
  if (threadIdx.x == 0) {
    while (__hip_atomic_load(genp, __ATOMIC_ACQUIRE, __HIP_MEMORY_SCOPE_AGENT) < g)
      __builtin_amdgcn_s_sleep(1);
    __threadfence();  // discard stale cached lines before consuming
  }
  __syncthreads();
}

// ---------------------------------------------------------------------------
// Persistent decoder: all 128 steps, 4 phases per step, grid barriers between.
// ---------------------------------------------------------------------------
__global__ __launch_bounds__(NTHR) void decoder_fused(
    const float* __restrict__ emb, const float* __restrict__ dec,
    const float* __restrict__ ctx, const float* __restrict__ Wi,
    const float* __restrict__ bi, const float* __restrict__ Wh,
    const float* __restrict__ bh, const float* __restrict__ Wha,
    const float* __restrict__ v, const float* __restrict__ Wout,
    const float* __restrict__ bout, const float* __restrict__ ctxp,
    float* __restrict__ gates, float* __restrict__ g_h,
    float* __restrict__ c0buf, float* __restrict__ c1buf,
    float* __restrict__ g_q, float* __restrict__ g_hp,
    float* __restrict__ g_att, float* __restrict__ g_msk,
    int* __restrict__ g_sel, int* __restrict__ barslots,
    int* __restrict__ bargen, float* __restrict__ out) {
  const int bid = blockIdx.x;
  const int tid = threadIdx.x;

  __shared__ union {
    struct { float As[64][36]; float Bs[64][64]; } p1;                 // 25.2 KB
    struct { float hi[16][512]; float Bs[64][68]; } p2;                // 49.8 KB
    struct { float es[128]; float attp[8][512]; float red[4]; int redi[2]; } p3; // ~17 KB
    struct { float As[64][36]; float Bs[64][20]; } p4;                 // 14.2 KB
  } sh;

  for (int t = 0; t < S; ++t) {
    const int gb = t * 4;
    const float* cr = (t & 1) ? c1buf : c0buf;
    float* cw = (t & 1) ? c0buf : c1buf;

    // ============ P1: gates = h@Wh + gather(x)@Wi + bi + bh ============
    {
      const int m0 = (bid >> 5) * 32;   // 8 m-tiles of 32 rows
      const int n0 = (bid & 31) * 64;   // 32 n-tiles of 64 cols (N=2048)
      const int tm = tid >> 5;          // 0..15
      const int tn = tid & 31;          // 0..31
      float acc00 = 0.f, acc01 = 0.f, acc10 = 0.f, acc11 = 0.f;

      const int srow = tid >> 4;          // 0..31 (staging row)
      const int skq = (tid & 15) * 4;     // 0..60 (staging k quad)

      for (int part = 0; part < 2; ++part) {
        const float* Wp = part ? Wi : Wh;
        const float* ar;
        if (part == 0) {
          ar = g_h + (size_t)(m0 + srow) * H;
        } else if (t == 0) {
          ar = dec + (size_t)(m0 + srow) * H;
        } else {
          ar = emb + ((size_t)(m0 + srow) * S + g_sel[m0 + srow]) * H;
        }
        for (int kk = 0; kk < H; kk += 64) {
          float4 a4 = *reinterpret_cast<const float4*>(ar + kk + skq);
          sh.p1.As[skq + 0][srow] = a4.x;
          sh.p1.As[skq + 1][srow] = a4.y;
          sh.p1.As[skq + 2][srow] = a4.z;
          sh.p1.As[skq + 3][srow] = a4.w;
#pragma unroll
          for (int i = 0; i < 2; ++i) {
            int lin = tid + i * 512;
            int k = lin >> 4, c4 = (lin & 15) * 4;
            *reinterpret_cast<float4*>(&sh.p1.Bs[k][c4]) =
                *reinterpret_cast<const float4*>(Wp + (size_t)(kk + k) * 2048 + n0 + c4);
          }
          __syncthreads();
#pragma unroll 8
          for (int k = 0; k < 64; ++k) {
            float2 a = *reinterpret_cast<const float2*>(&sh.p1.As[k][tm * 2]);
            float2 b = *reinterpret_cast<const float2*>(&sh.p1.Bs[k][tn * 2]);
            acc00 = fmaf(a.x, b.x, acc00);
            acc01 = fmaf(a.x, b.y, acc01);
            acc10 = fmaf(a.y, b.x, acc10);
            acc11 = fmaf(a.y, b.y, acc11);
          }
          __syncthreads();
        }
      }
      const int r0 = m0 + tm * 2, cA = n0 + tn * 2;
      float bb0 = bi[cA] + bh[cA], bb1 = bi[cA + 1] + bh[cA + 1];
      *reinterpret_cast<float2*>(&gates[(size_t)r0 * 2048 + cA]) =
          make_float2(acc00 + bb0, acc01 + bb1);
      *reinterpret_cast<float2*>(&gates[(size_t)(r0 + 1) * 2048 + cA]) =
          make_float2(acc10 + bb0, acc11 + bb1);
    }
    grid_barrier(barslots, bargen, gb + 1);

    // ============ P2: cell (into LDS) + [q | hpart] = h_i @ [Wha | Wout2] ====
    {
      const int mt = bid >> 4, nt = bid & 15;
      const int m0 = mt * 16;
      const bool isq = nt < 8;
      const float* Wp = isq ? Wha : (Wout + (size_t)H * H);
      const int n0 = (isq ? nt : nt - 8) * 64;
      float* Co = isq ? g_q : g_hp;

      for (int r = 0; r < 16; ++r) {
        size_t gbse = (size_t)(m0 + r) * 2048 + tid;
        float gi = sigmf(gates[gbse]);
        float gf = sigmf(gates[gbse + 512]);
        float gg = sigmf(gates[gbse + 1024]);
        float go = sigmf(gates[gbse + 1536]);
        float cn = gf * cr[(size_t)(m0 + r) * H + tid] + gi * gg;
        if (nt == 0) cw[(size_t)(m0 + r) * H + tid] = cn;
        sh.p2.hi[r][tid] = go * tanhf(cn);
      }
      __syncthreads();

      const int tm = tid >> 5;   // 0..15
      const int tn = tid & 31;   // 0..31
      float a0 = 0.f, a1 = 0.f;
      for (int kk = 0; kk < H; kk += 64) {
#pragma unroll
        for (int i = 0; i < 2; ++i) {
          int lin = tid + i * 512;
          int k = lin >> 4, c4 = (lin & 15) * 4;
          *reinterpret_cast<float4*>(&sh.p2.Bs[k][c4]) =
              *reinterpret_cast<const float4*>(Wp + (size_t)(kk + k) * H + n0 + c4);
        }
        __syncthreads();
#pragma unroll 8
        for (int k = 0; k < 64; ++k) {
          float av = sh.p2.hi[tm][kk + k];
          float2 b = *reinterpret_cast<const float2*>(&sh.p2.Bs[k][tn * 2]);
          a0 = fmaf(av, b.x, a0);
          a1 = fmaf(av, b.y, a1);
        }
        __syncthreads();
      }
      *reinterpret_cast<float2*>(&Co[(size_t)(m0 + tm) * H + n0 + tn * 2]) =
          make_float2(a0, a1);
    }
    grid_barrier(barslots, bargen, gb + 2);

    // ============ P3: fused scores+softmax+argmax+att, masked-row skip ======
    {
      const int b = bid;
      const int wv = tid >> 6;   // wave 0..7, owns s in [wv*16, wv*16+16)
      const int ln = tid & 63;   // lane
      const int col = ln * 8;    // lane owns h-cols [col, col+8)

      const float* qb = g_q + (size_t)b * H + col;
      float4 qv0 = *reinterpret_cast<const float4*>(qb);
      float4 qv1 = *reinterpret_cast<const float4*>(qb + 4);
      float4 vv0 = *reinterpret_cast<const float4*>(v + col);
      float4 vv1 = *reinterpret_cast<const float4*>(v + col + 4);

      // wave's 16 mask values live in lanes 0..15 (broadcast via shfl)
      float mk16 = g_msk[(size_t)b * S + wv * 16 + (ln & 15)];

      float a0 = 0.f, a1 = 0.f, a2 = 0.f, a3 = 0.f;
      float a4 = 0.f, a5 = 0.f, a6 = 0.f, a7 = 0.f;
      const float* cpb = ctxp + ((size_t)b * S + wv * 16) * H + col;
      const float* cxb = ctx + ((size_t)b * S + wv * 16) * H + col;

      for (int i = 0; i < 16; ++i) {
        float mk = __shfl(mk16, i);
        int sIdx = wv * 16 + i;
        if (mk != 0.f) {
          float4 p0 = *reinterpret_cast<const float4*>(cpb + (size_t)i * H);
          float4 p1 = *reinterpret_cast<const float4*>(cpb + (size_t)i * H + 4);
          float4 x0 = *reinterpret_cast<const float4*>(cxb + (size_t)i * H);
          float4 x1 = *reinterpret_cast<const float4*>(cxb + (size_t)i * H + 4);
          float t0 = vv0.x * tanhf(p0.x + qv0.x);
          float t1 = vv0.y * tanhf(p0.y + qv0.y);
          float t2 = vv0.z * tanhf(p0.z + qv0.z);
          float t3 = vv0.w * tanhf(p0.w + qv0.w);
          float t4 = vv1.x * tanhf(p1.x + qv1.x);
          float t5 = vv1.y * tanhf(p1.y + qv1.y);
          float t6 = vv1.z * tanhf(p1.z + qv1.z);
          float t7 = vv1.w * tanhf(p1.w + qv1.w);
          float part = ((t0 + t1) + (t2 + t3)) + ((t4 + t5) + (t6 + t7));
#pragma unroll
          for (int o = 1; o < 64; o <<= 1) part += __shfl_xor(part, o);
          float e = expf(part);   // no max-subtraction: |score| <= ~8, safe
          if (ln == 0) sh.p3.es[sIdx] = e;
          a0 = fmaf(e, x0.x, a0);
          a1 = fmaf(e, x0.y, a1);
          a2 = fmaf(e, x0.z, a2);
          a3 = fmaf(e, x0.w, a3);
          a4 = fmaf(e, x1.x, a4);
          a5 = fmaf(e, x1.y, a5);
          a6 = fmaf(e, x1.z, a6);
          a7 = fmaf(e, x1.w, a7);
        } else if (ln == 0) {
          sh.p3.es[sIdx] = 0.f;   // matches ref: exp(-1e9-m) underflows to 0
        }
      }
      // wave partial of unnormalized att -> LDS
      float* ap = &sh.p3.attp[wv][col];
      ap[0] = a0; ap[1] = a1; ap[2] = a2; ap[3] = a3;
      ap[4] = a4; ap[5] = a5; ap[6] = a6; ap[7] = a7;
      __syncthreads();

      // sum of e over 128 s (threads 0..127)
      float e = (tid < 128) ? sh.p3.es[tid] : 0.f;
      float wsum = e;
#pragma unroll
      for (int o = 1; o < 64; o <<= 1) wsum += __shfl_xor(wsum, o);
      if (tid < 128 && (tid & 63) == 0) sh.p3.red[tid >> 6] = wsum;
      __syncthreads();
      const float sum = sh.p3.red[0] + sh.p3.red[1];

      // alpha + output write + argmax (masked entries are exactly 0)
      float a = e / sum;
      if (tid < 128) out[((size_t)b * S + t) * S + tid] = a;

      float mv = (tid < 128) ? a : -1.f;
      int mi = tid & 127;
#pragma unroll
      for (int o = 1; o < 64; o <<= 1) {
        float ov = __shfl_xor(mv, o);
        int oi = __shfl_xor(mi, o);
        if (ov > mv || (ov == mv && oi < mi)) { mv = ov; mi = oi; }
      }
      if (tid < 128 && (tid & 63) == 0) {
        sh.p3.red[2 + (tid >> 6)] = mv;
        sh.p3.redi[tid >> 6] = mi;
      }
      __syncthreads();
      if (tid == 0) {
        float bv = sh.p3.red[2];
        int bI = sh.p3.redi[0];
        if (sh.p3.red[3] > bv || (sh.p3.red[3] == bv && sh.p3.redi[1] < bI)) {
          bv = sh.p3.red[3];
          bI = sh.p3.redi[1];
        }
        out[(size_t)B * S * S + (size_t)b * S + t] = (float)bI;  // pointers[b,t]
        g_msk[(size_t)b * S + bI] = 0.f;
        g_sel[b] = bI;
      }

      // att finalize: att[b, tid] = (sum over 8 wave partials) / sum_e
      float acc = 0.f;
#pragma unroll
      for (int w = 0; w < 8; ++w) acc += sh.p3.attp[w][tid];
      g_att[(size_t)b * H + tid] = acc / sum;
    }
    grid_barrier(barslots, bargen, gb + 3);

    // ============ P4: h = tanh(att@Wout1 + hpart + bout) ============
    {
      const int m0 = (bid >> 5) * 32;   // 8 m-tiles of 32
      const int n0 = (bid & 31) * 16;   // 32 n-tiles of 16 (N=512)
      const int tm = tid >> 4;          // 0..31
      const int tn = tid & 15;          // 0..15
      float acc = 0.f;
      const int srow = tid >> 4, skq = (tid & 15) * 4;
      for (int kk = 0; kk < H; kk += 64) {
        float4 a4 = *reinterpret_cast<const float4*>(
            g_att + (size_t)(m0 + srow) * H + kk + skq);
        sh.p4.As[skq + 0][srow] = a4.x;
        sh.p4.As[skq + 1][srow] = a4.y;
        sh.p4.As[skq + 2][srow] = a4.z;
        sh.p4.As[skq + 3][srow] = a4.w;
        if (tid < 256) {
          int k = tid >> 2, c4 = (tid & 3) * 4;
          *reinterpret_cast<float4*>(&sh.p4.Bs[k][c4]) =
              *reinterpret_cast<const float4*>(Wout + (size_t)(kk + k) * H + n0 + c4);
        }
        __syncthreads();
#pragma unroll 8
        for (int k = 0; k < 64; ++k)
          acc = fmaf(sh.p4.As[k][tm], sh.p4.Bs[k][tn], acc);
        __syncthreads();
      }
      float x = acc + g_hp[(size_t)(m0 + tm) * H + n0 + tn] + bout[n0 + tn];
      g_h[(size_t)(m0 + tm) * H + n0 + tn] = tanhf(x);
    }
    grid_barrier(barslots, bargen, gb + 4);
  }
}

}  // namespace

// ---------------------------------------------------------------------------
extern "C" void kernel_launch(void* const* d_in, const int* in_sizes, int n_in,
                              void* d_out, int out_size, void* d_ws, size_t ws_size,
                              hipStream_t stream) {
  const float* emb  = (const float*)d_in[0];   // (B,S,H)
  const float* dec  = (const float*)d_in[1];   // (B,H)
  const float* h0   = (const float*)d_in[2];   // (B,H)
  const float* c0   = (const float*)d_in[3];   // (B,H)
  const float* ctx  = (const float*)d_in[4];   // (B,S,H)
  const float* Wi   = (const float*)d_in[5];   // (H,4H)
  const float* bi   = (const float*)d_in[6];   // (4H)
  const float* Wh   = (const float*)d_in[7];   // (H,4H)
  const float* bh   = (const float*)d_in[8];   // (4H)
  const float* Wctx = (const float*)d_in[9];   // (H,H)
  const float* Wha  = (const float*)d_in[10];  // (H,H)
  const float* v    = (const float*)d_in[11];  // (H)
  const float* Wout = (const float*)d_in[12];  // (2H,H)
  const float* bout = (const float*)d_in[13];  // (H)
  float* out = (float*)d_out;

  // workspace layout (floats)
  float* ws = (float*)d_ws;
  float* ctxp  = ws;                            // B*S*H = 16,777,216
  float* gates = ctxp + (size_t)B * S * H;      // B*4H
  float* g_h   = gates + (size_t)B * 4 * H;     // B*H
  float* c0buf = g_h + (size_t)B * H;           // B*H
  float* c1buf = c0buf + (size_t)B * H;         // B*H
  float* g_q   = c1buf + (size_t)B * H;         // B*H
  float* g_hp  = g_q + (size_t)B * H;           // B*H
  float* g_att = g_hp + (size_t)B * H;          // B*H
  float* g_msk = g_att + (size_t)B * H;         // B*S
  int*   g_sel = (int*)(g_msk + (size_t)B * S); // B
  int*   bar   = g_sel + B;                     // slots[256] + gen

  init_kernel<<<(B * H + 511) / 512, 512, 0, stream>>>(g_h, c0buf, g_msk, bar, h0, c0);

  // ctx_proj = context @ Wctx   (32768 x 512, K=512)
  gemm_pre<128, 64, 8, 4, 16><<<dim3(H / 64, (B * S) / 128), 256, 0, stream>>>(
      ctx, Wctx, ctxp, B * S, H, H);

  decoder_fused<<<NBLK, NTHR, 0, stream>>>(
      emb, dec, ctx, Wi, bi, Wh, bh, Wha, v, Wout, bout, ctxp,
      gates, g_h, c0buf, c1buf, g_q, g_hp, g_att, g_msk, g_sel,
      bar, bar + NBLK, out);
}